// Round 11
// baseline (256.134 us; speedup 1.0000x reference)
//
#include <hip/hip_runtime.h>
#include <hip/hip_bf16.h>

#define ENC 2048
#define ADIM 512
#define DEC 512
#define NBATCH 128
#define NL 196
#define MTOT (NBATCH * NL)   // 25088
#define NKT 32               // K-steps of 64

typedef __attribute__((ext_vector_type(8))) short short8;
typedef __attribute__((ext_vector_type(4))) float f32x4;
typedef __attribute__((ext_vector_type(4))) unsigned int u32x4;

__device__ __forceinline__ unsigned short f2bf(float f) {
    __hip_bfloat16 h = __float2bfloat16(f);
    union { __hip_bfloat16 h; unsigned short u; } cv; cv.h = h; return cv.u;
}
__device__ __forceinline__ unsigned int f2bf2(float lo, float hi) {
    __hip_bfloat162 h = __float22bfloat162_rn(float2{lo, hi});
    union { __hip_bfloat162 h; unsigned int u; } cv; cv.h = h; return cv.u;
}

// async global -> LDS, 16B per lane. lds pointer must be wave-uniform.
__device__ __forceinline__ void load_lds16(const void* g, void* l) {
    __builtin_amdgcn_global_load_lds(
        (const __attribute__((address_space(1))) unsigned int*)g,
        (__attribute__((address_space(3))) unsigned int*)l, 16, 0, 0);
}

// ---------------- kernel 1: w_ah = hidden @ W_w + W_b  [128 x 512] ----------------
__global__ void wah_kernel(const float* __restrict__ hidden, const float* __restrict__ Ww,
                           const float* __restrict__ Wb, float* __restrict__ wah) {
    __shared__ __align__(16) float hs[DEC];
    const int b = blockIdx.x, a = threadIdx.x;   // block 512 threads
    hs[a] = hidden[b * DEC + a];
    __syncthreads();
    float acc = Wb[a];
    #pragma unroll 4
    for (int d = 0; d < DEC; d += 4) {
        f32x4 h = *(const f32x4*)&hs[d];
        acc += h.x * Ww[(d    ) * ADIM + a];
        acc += h.y * Ww[(d + 1) * ADIM + a];
        acc += h.z * Ww[(d + 2) * ADIM + a];
        acc += h.w * Ww[(d + 3) * ADIM + a];
    }
    wah[b * ADIM + a] = acc;
}

// ---------------- kernel 2: U_w [K=2048][N=512] fp32 -> uwT [N][K] bf16 ----------------
__global__ void transpose_uw(const float* __restrict__ Uw, unsigned short* __restrict__ uwT) {
    __shared__ float t[32][33];
    const int k0 = blockIdx.x * 32, n0 = blockIdx.y * 32;
    const int tx = threadIdx.x, ty = threadIdx.y;   // 32 x 8
    #pragma unroll
    for (int i = 0; i < 4; ++i)
        t[ty + 8 * i][tx] = Uw[(size_t)(k0 + ty + 8 * i) * ADIM + n0 + tx];
    __syncthreads();
    #pragma unroll
    for (int i = 0; i < 4; ++i)
        uwT[(size_t)(n0 + ty + 8 * i) * ENC + k0 + tx] = f2bf(t[tx][ty + 8 * i]);
}

// ---------------- kernel 3: fused GEMM + tanh + A_w-dot -> score partials ----------------
// R9 structure (single-buffer 32KB LDS, 4 blocks/CU, all 784 blocks co-resident)
// but NO cvt pre-pass: A is reg-staged from fp32 feat with in-kernel bf16
// conversion, pipelined with counted vmcnt + raw barriers (R4-proven choreography):
//   steady state per step: A(t+1) regs arrive with a full compute phase of
//   latency cover; manual vmcnt(8) drains only B(t)'s 4 DMAs; A(t+2)'s 8 loads
//   stay in flight across the barrier. sched_barrier(0) after each asm wait
//   (rule #18). B: global_load_lds DMA, pre-swizzled source (R9-proven, 0 conflicts).
__global__ __launch_bounds__(256, 4) void gemm_score(
    const float* __restrict__ feat, const unsigned short* __restrict__ uwT,
    const float* __restrict__ Ub, const float* __restrict__ wahb,
    const float* __restrict__ Aw, float* __restrict__ part)
{
    __shared__ __align__(16) unsigned char As[16384];   // [128][64] bf16 swizzled
    __shared__ __align__(16) unsigned char Bs[16384];   // [128][64] bf16 swizzled

    const int tid  = threadIdx.x;
    const int lane = tid & 63;
    const int w    = tid >> 6;
    const int wr   = w >> 1, wc = w & 1;
    const int l15  = lane & 15, ldr = lane >> 4;

    // bijective XCD swizzle: 784 blocks = 8 XCD chunks of 98 (nbk fastest -> A-panel shared in L2)
    const int bid  = blockIdx.x;
    const int work = (bid & 7) * 98 + (bid >> 3);
    const int mb   = work >> 2;    // 0..195
    const int nbk  = work & 3;     // 0..3

    // ---- A staging: thread -> row r_=tid>>1, k-half h_=tid&1 (32 floats = 8 f32x4) ----
    const int r_ = tid >> 1, h_ = tid & 1;
    const float* aSrc = feat + (size_t)(mb * 128 + r_) * ENC + h_ * 32;
    int wA[4];
    #pragma unroll
    for (int j = 0; j < 4; ++j)
        wA[j] = r_ * 128 + (((h_ * 4 + j) ^ (r_ & 7)) << 4);

    // ---- B DMA source (pre-swizzled, R9): wave w rows w*32..+31, 4 chunks of 8 rows ----
    const int swz = ((lane & 7) ^ ((lane >> 3) & 7)) << 3;   // bf16 elems
    const unsigned short* bS = uwT + (size_t)(nbk * 128 + w * 32 + (lane >> 3)) * ENC + swz;

    // ---- fragment read offsets (swizzled, 0-conflict): slot (ks*4+ldr) ^ (row&7) ----
    int abyte[4][2], bbyte[4][2];
    #pragma unroll
    for (int f = 0; f < 4; ++f) {
        const int ra = wr * 64 + f * 16 + l15;
        const int rb = wc * 64 + f * 16 + l15;
        #pragma unroll
        for (int ks = 0; ks < 2; ++ks) {
            abyte[f][ks] = ra * 128 + (((ks * 4 + ldr) ^ (ra & 7)) << 4);
            bbyte[f][ks] = rb * 128 + (((ks * 4 + ldr) ^ (rb & 7)) << 4);
        }
    }

    f32x4 acc[4][4];
    #pragma unroll
    for (int i = 0; i < 4; ++i)
        #pragma unroll
        for (int j = 0; j < 4; ++j)
            acc[i][j] = (f32x4){0.f, 0.f, 0.f, 0.f};

    f32x4 ar0, ar1, ar2, ar3, ar4, ar5, ar6, ar7;   // A(t) fp32 stage regs

#define LOAD_A(KT) {                                                          \
    const f32x4* p = (const f32x4*)(aSrc + (size_t)(KT) * 64);                \
    ar0 = p[0]; ar1 = p[1]; ar2 = p[2]; ar3 = p[3];                           \
    ar4 = p[4]; ar5 = p[5]; ar6 = p[6]; ar7 = p[7];                           \
    __builtin_amdgcn_sched_barrier(0);                                        \
}
#define DMA_B(KT) {                                                           \
    _Pragma("unroll")                                                         \
    for (int c = 0; c < 4; ++c)                                               \
        load_lds16(bS + (size_t)(KT) * 64 + c * 8 * ENC,                      \
                   Bs + w * 4096 + c * 1024);                                 \
    __builtin_amdgcn_sched_barrier(0);                                        \
}
#define CVTW() {                                                              \
    u32x4 w0, w1, w2, w3;                                                     \
    w0.x = f2bf2(ar0.x, ar0.y); w0.y = f2bf2(ar0.z, ar0.w);                   \
    w0.z = f2bf2(ar1.x, ar1.y); w0.w = f2bf2(ar1.z, ar1.w);                   \
    w1.x = f2bf2(ar2.x, ar2.y); w1.y = f2bf2(ar2.z, ar2.w);                   \
    w1.z = f2bf2(ar3.x, ar3.y); w1.w = f2bf2(ar3.z, ar3.w);                   \
    w2.x = f2bf2(ar4.x, ar4.y); w2.y = f2bf2(ar4.z, ar4.w);                   \
    w2.z = f2bf2(ar5.x, ar5.y); w2.w = f2bf2(ar5.z, ar5.w);                   \
    w3.x = f2bf2(ar6.x, ar6.y); w3.y = f2bf2(ar6.z, ar6.w);                   \
    w3.z = f2bf2(ar7.x, ar7.y); w3.w = f2bf2(ar7.z, ar7.w);                   \
    *(u32x4*)(As + wA[0]) = w0;                                               \
    *(u32x4*)(As + wA[1]) = w1;                                               \
    *(u32x4*)(As + wA[2]) = w2;                                               \
    *(u32x4*)(As + wA[3]) = w3;                                               \
}
#define COMPUTE() {                                                           \
    __builtin_amdgcn_s_setprio(1);                                            \
    _Pragma("unroll")                                                         \
    for (int ks = 0; ks < 2; ++ks) {                                          \
        short8 af[4], bf[4];                                                  \
        _Pragma("unroll")                                                     \
        for (int f = 0; f < 4; ++f) {                                         \
            af[f] = *(const short8*)(As + abyte[f][ks]);                      \
            bf[f] = *(const short8*)(Bs + bbyte[f][ks]);                      \
        }                                                                     \
        _Pragma("unroll")                                                     \
        for (int fm = 0; fm < 4; ++fm)                                        \
            _Pragma("unroll")                                                 \
            for (int fn = 0; fn < 4; ++fn)                                    \
                acc[fm][fn] = __builtin_amdgcn_mfma_f32_16x16x32_bf16(        \
                    af[fm], bf[fn], acc[fm][fn], 0, 0, 0);                    \
    }                                                                         \
    __builtin_amdgcn_s_setprio(0);                                            \
    __builtin_amdgcn_sched_barrier(0);                                        \
}

    // ---- prologue: stage tile 0, put A(1) in flight ----
    LOAD_A(0);
    DMA_B(0);
    CVTW();                                   // compiler emits exact vmcnt for A(0) regs
    LOAD_A(1);
    asm volatile("s_waitcnt vmcnt(8)");       // drain B(0)'s 4 DMAs (A(1)'s 8 stay in flight)
    __builtin_amdgcn_sched_barrier(0);
    asm volatile("s_waitcnt lgkmcnt(0)");     // ds_writes visible
    __builtin_amdgcn_sched_barrier(0);
    __builtin_amdgcn_s_barrier();             // tile 0 ready

    #pragma unroll 1
    for (int kt = 0; kt < NKT; ++kt) {
        COMPUTE();                            // tile kt
        if (kt < NKT - 1) {
            __builtin_amdgcn_s_barrier();     // all waves done reading tile kt
            DMA_B(kt + 1);                    // overwrite Bs
            CVTW();                           // write As(kt+1); auto-wait for A(kt+1) regs
            const int k2 = (kt + 2 < NKT) ? kt + 2 : NKT - 1;
            LOAD_A(k2);                       // in flight across next compute
            asm volatile("s_waitcnt vmcnt(8)");   // drain B(kt+1); A(k2) stays out
            __builtin_amdgcn_sched_barrier(0);
            asm volatile("s_waitcnt lgkmcnt(0)");
            __builtin_amdgcn_sched_barrier(0);
            __builtin_amdgcn_s_barrier();     // tile kt+1 ready
        }
    }
#undef LOAD_A
#undef DMA_B
#undef CVTW
#undef COMPUTE

    // epilogue: score partial = sum_c Aw[c] * tanh(acc + Ub[c] + wah[b][c])
    float ub4[4], aw4[4]; int cidx[4];
    #pragma unroll
    for (int f = 0; f < 4; ++f) {
        const int c = nbk * 128 + wc * 64 + f * 16 + l15;
        cidx[f] = c; ub4[f] = Ub[c]; aw4[f] = Aw[c];
    }
    #pragma unroll
    for (int fm = 0; fm < 4; ++fm) {
        #pragma unroll
        for (int r = 0; r < 4; ++r) {
            const int m = mb * 128 + wr * 64 + fm * 16 + ldr * 4 + r;
            const int b = m / NL;
            const float* wrow = wahb + b * ADIM;
            float s = 0.f;
            #pragma unroll
            for (int f = 0; f < 4; ++f)
                s += aw4[f] * tanhf(acc[fm][f][r] + ub4[f] + wrow[cidx[f]]);
            s += __shfl_xor(s, 1);
            s += __shfl_xor(s, 2);
            s += __shfl_xor(s, 4);
            s += __shfl_xor(s, 8);
            if (l15 == 0) part[(nbk * 2 + wc) * MTOT + m] = s;
        }
    }
}

// ---------------- kernel 4: reduce partials + softmax over L -> alpha ----------------
__global__ void softmax_kernel(const float* __restrict__ part, const float* __restrict__ Ab,
                               float* __restrict__ alpha) {
    const int b = blockIdx.x, t = threadIdx.x;   // 256 threads
    float sv = 0.f;
    if (t < NL) {
        sv = Ab[0];
        #pragma unroll
        for (int p = 0; p < 8; ++p) sv += part[p * MTOT + b * NL + t];
    }
    float v = (t < NL) ? sv : -3.4e38f;
    #pragma unroll
    for (int o = 32; o >= 1; o >>= 1) v = fmaxf(v, __shfl_xor(v, o));
    __shared__ float rm[4], rs[4];
    if ((t & 63) == 0) rm[t >> 6] = v;
    __syncthreads();
    const float bm = fmaxf(fmaxf(rm[0], rm[1]), fmaxf(rm[2], rm[3]));
    const float e = (t < NL) ? expf(sv - bm) : 0.f;
    float s = e;
    #pragma unroll
    for (int o = 32; o >= 1; o >>= 1) s += __shfl_xor(s, o);
    if ((t & 63) == 0) rs[t >> 6] = s;
    __syncthreads();
    const float bs = rs[0] + rs[1] + rs[2] + rs[3];
    if (t < NL) alpha[b * NL + t] = e / bs;
}

// ---------------- kernel 5: context[b][e] = sum_l alpha[b][l] * feat[b][l][e] ----------------
__global__ void context_kernel(const float* __restrict__ feat, const float* __restrict__ alpha,
                               float* __restrict__ ctx) {
    __shared__ float al[NL];
    const int b = blockIdx.x, chunk = blockIdx.y, t = threadIdx.x;  // 128 threads
    for (int i = t; i < NL; i += 128) al[i] = alpha[b * NL + i];
    __syncthreads();
    const int e0 = chunk * 512 + t * 4;
    const float* fp = feat + (size_t)b * NL * ENC + e0;
    f32x4 acc0 = (f32x4){0.f, 0.f, 0.f, 0.f};
    f32x4 acc1 = (f32x4){0.f, 0.f, 0.f, 0.f};
    #pragma unroll 2
    for (int l = 0; l < NL; l += 2) {
        f32x4 f0 = *(const f32x4*)(fp + (size_t)l * ENC);
        f32x4 f1 = *(const f32x4*)(fp + (size_t)(l + 1) * ENC);
        acc0 += al[l] * f0;
        acc1 += al[l + 1] * f1;
    }
    f32x4 rsum = acc0 + acc1;
    *(f32x4*)(ctx + (size_t)b * ENC + e0) = rsum;
}

extern "C" void kernel_launch(void* const* d_in, const int* in_sizes, int n_in,
                              void* d_out, int out_size, void* d_ws, size_t ws_size,
                              hipStream_t stream) {
    const float* feat   = (const float*)d_in[0];
    const float* hidden = (const float*)d_in[1];
    const float* Uw     = (const float*)d_in[2];
    const float* Ub     = (const float*)d_in[3];
    const float* Ww     = (const float*)d_in[4];
    const float* Wb     = (const float*)d_in[5];
    const float* Aw     = (const float*)d_in[6];
    const float* Ab     = (const float*)d_in[7];

    float* out   = (float*)d_out;
    float* alpha = out;              // [128*196]
    float* ctx   = out + MTOT;       // [128*2048]

    char* ws = (char*)d_ws;
    float*          wahb  = (float*)ws;                          // 256 KB
    unsigned short* uwT   = (unsigned short*)(ws + 262144);      // 2 MB
    float*          partb = (float*)(ws + 262144 + 2097152);     // 784 KB

    wah_kernel<<<dim3(128), dim3(512), 0, stream>>>(hidden, Ww, Wb, wahb);
    transpose_uw<<<dim3(64, 16), dim3(32, 8), 0, stream>>>(Uw, uwT);
    gemm_score<<<dim3(784), dim3(256), 0, stream>>>(feat, uwT, Ub, wahb, Aw, partb);
    softmax_kernel<<<dim3(128), dim3(256), 0, stream>>>(partb, Ab, alpha);
    context_kernel<<<dim3(128, 4), dim3(128), 0, stream>>>(feat, alpha, ctx);
}

// Round 12
// 187.732 us; speedup vs baseline: 1.3644x; 1.3644x over previous
//
#include <hip/hip_runtime.h>
#include <hip/hip_bf16.h>

#define ENC 2048
#define ADIM 512
#define DEC 512
#define NBATCH 128
#define NL 196
#define MTOT (NBATCH * NL)   // 25088
#define NKT 32               // K-steps of 64

typedef __attribute__((ext_vector_type(8))) short short8;
typedef __attribute__((ext_vector_type(4))) float f32x4;
typedef __attribute__((ext_vector_type(4))) unsigned int u32x4;

__device__ __forceinline__ unsigned short f2bf(float f) {
    __hip_bfloat16 h = __float2bfloat16(f);
    union { __hip_bfloat16 h; unsigned short u; } cv; cv.h = h; return cv.u;
}
__device__ __forceinline__ unsigned int f2bf2(float lo, float hi) {
    __hip_bfloat162 h = __float22bfloat162_rn(float2{lo, hi});
    union { __hip_bfloat162 h; unsigned int u; } cv; cv.h = h; return cv.u;
}

// async global -> LDS, 16B per lane. lds pointer must be wave-uniform.
__device__ __forceinline__ void load_lds16(const void* g, void* l) {
    __builtin_amdgcn_global_load_lds(
        (const __attribute__((address_space(1))) unsigned int*)g,
        (__attribute__((address_space(3))) unsigned int*)l, 16, 0, 0);
}

// ---------------- kernel 1: w_ah = hidden @ W_w + W_b  [128 x 512] ----------------
__global__ void wah_kernel(const float* __restrict__ hidden, const float* __restrict__ Ww,
                           const float* __restrict__ Wb, float* __restrict__ wah) {
    __shared__ __align__(16) float hs[DEC];
    const int b = blockIdx.x, a = threadIdx.x;   // block 512 threads
    hs[a] = hidden[b * DEC + a];
    __syncthreads();
    float acc = Wb[a];
    #pragma unroll 4
    for (int d = 0; d < DEC; d += 4) {
        f32x4 h = *(const f32x4*)&hs[d];
        acc += h.x * Ww[(d    ) * ADIM + a];
        acc += h.y * Ww[(d + 1) * ADIM + a];
        acc += h.z * Ww[(d + 2) * ADIM + a];
        acc += h.w * Ww[(d + 3) * ADIM + a];
    }
    wah[b * ADIM + a] = acc;
}

// ---------------- kernel 2: U_w [K=2048][N=512] fp32 -> uwT [N][K] bf16 ----------------
__global__ void transpose_uw(const float* __restrict__ Uw, unsigned short* __restrict__ uwT) {
    __shared__ float t[32][33];
    const int k0 = blockIdx.x * 32, n0 = blockIdx.y * 32;
    const int tx = threadIdx.x, ty = threadIdx.y;   // 32 x 8
    #pragma unroll
    for (int i = 0; i < 4; ++i)
        t[ty + 8 * i][tx] = Uw[(size_t)(k0 + ty + 8 * i) * ADIM + n0 + tx];
    __syncthreads();
    #pragma unroll
    for (int i = 0; i < 4; ++i)
        uwT[(size_t)(n0 + ty + 8 * i) * ENC + k0 + tx] = f2bf(t[tx][ty + 8 * i]);
}

// ---------------- kernel 3: fused GEMM + tanh + A_w-dot -> score partials ----------------
// m97-exact single-buffer 2-barrier loop (the ONLY structure that has performed),
// but A stays fp32: staged via global_load_lds into a [128][64] fp32 tile (32KB)
// and converted to bf16 at fragment-read time (cvt hides under MFMA via m114
// cross-wave co-issue). NO cvt pre-pass => HBM floor drops 514->420 MB.
//  A swizzle (256B rows, 16 slots): slot ^= row&15. Reads hit 16 distinct slots
//    (2 lanes/bank = free, m136); DMA dest linear, source pre-swizzled.
//  B: bf16 uwT via DMA, R9-proven swizzle (slot ^= row&7), 0 conflicts.
// LDS 48KB -> 3 blocks/CU (784 blocks: 768 round-1 + 16 tail ~ +2%).
__global__ __launch_bounds__(256, 3) void gemm_score(
    const float* __restrict__ feat, const unsigned short* __restrict__ uwT,
    const float* __restrict__ Ub, const float* __restrict__ wahb,
    const float* __restrict__ Aw, float* __restrict__ part)
{
    __shared__ __align__(16) unsigned char As[32768];   // [128][64] fp32 swizzled
    __shared__ __align__(16) unsigned char Bs[16384];   // [128][64] bf16 swizzled

    const int tid  = threadIdx.x;
    const int lane = tid & 63;
    const int w    = tid >> 6;
    const int wr   = w >> 1, wc = w & 1;
    const int l15  = lane & 15, ldr = lane >> 4;

    // bijective XCD swizzle: 784 blocks = 8 XCD chunks of 98 (nbk fastest -> A-panel shared in L2)
    const int bid  = blockIdx.x;
    const int work = (bid & 7) * 98 + (bid >> 3);
    const int mb   = work >> 2;    // 0..195
    const int nbk  = work & 3;     // 0..3

    // ---- A DMA: 8 chunks/wave of 4 rows (1KB); lane -> row lane>>4, slot lane&15 ----
    // source pre-swizzled: src slot = (lane&15) ^ (rowL & 15), rowL = c*4 + (lane>>4) (w*32 drops out mod 16... w*32&15==0)
    const float* aS[8];
    #pragma unroll
    for (int c = 0; c < 8; ++c) {
        const int rowc = c * 4 + ldr;                     // row within wave's 32 (ldr = lane>>4)
        const int sslot = l15 ^ (rowc & 15);
        aS[c] = feat + (size_t)(mb * 128 + w * 32 + rowc) * ENC + sslot * 4;
    }
    // ---- B DMA source (pre-swizzled, R9): wave w rows w*32..+31, 4 chunks of 8 rows ----
    const int swzB = ((lane & 7) ^ ((lane >> 3) & 7)) << 3;   // bf16 elems
    const unsigned short* bS = uwT + (size_t)(nbk * 128 + w * 32 + (lane >> 3)) * ENC + swzB;

    // ---- fragment read offsets ----
    // A (fp32): row ra, k-slot q' = ks*8 + ldr*2 + j (j=0,1); byte = ra*256 + ((q'^l15)<<4)
    int abyte[4][2][2];
    // B (bf16): row rb, slot (ks*4+ldr) ^ (rb&7); byte = rb*128 + (..<<4)
    int bbyte[4][2];
    #pragma unroll
    for (int f = 0; f < 4; ++f) {
        const int ra = wr * 64 + f * 16 + l15;
        const int rb = wc * 64 + f * 16 + l15;
        #pragma unroll
        for (int ks = 0; ks < 2; ++ks) {
            abyte[f][ks][0] = ra * 256 + (((ks * 8 + ldr * 2 + 0) ^ l15) << 4);
            abyte[f][ks][1] = ra * 256 + (((ks * 8 + ldr * 2 + 1) ^ l15) << 4);
            bbyte[f][ks]    = rb * 128 + (((ks * 4 + ldr) ^ (rb & 7)) << 4);
        }
    }

    f32x4 acc[4][4];
    #pragma unroll
    for (int i = 0; i < 4; ++i)
        #pragma unroll
        for (int j = 0; j < 4; ++j)
            acc[i][j] = (f32x4){0.f, 0.f, 0.f, 0.f};

    #pragma unroll 1
    for (int kt = 0; kt < NKT; ++kt) {
        #pragma unroll
        for (int c = 0; c < 8; ++c)
            load_lds16(aS[c] + (size_t)kt * 64, As + w * 8192 + c * 1024);
        #pragma unroll
        for (int c = 0; c < 4; ++c)
            load_lds16(bS + (size_t)kt * 64 + c * 8 * ENC, Bs + w * 4096 + c * 1024);
        __syncthreads();   // drains DMA: tile ready

        #pragma unroll
        for (int ks = 0; ks < 2; ++ks) {
            short8 af[4], bf[4];
            #pragma unroll
            for (int f = 0; f < 4; ++f) {
                f32x4 lo = *(const f32x4*)(As + abyte[f][ks][0]);
                f32x4 hi = *(const f32x4*)(As + abyte[f][ks][1]);
                union { unsigned int u[4]; short8 s; } cv;
                cv.u[0] = f2bf2(lo.x, lo.y);
                cv.u[1] = f2bf2(lo.z, lo.w);
                cv.u[2] = f2bf2(hi.x, hi.y);
                cv.u[3] = f2bf2(hi.z, hi.w);
                af[f] = cv.s;
                bf[f] = *(const short8*)(Bs + bbyte[f][ks]);
            }
            #pragma unroll
            for (int fm = 0; fm < 4; ++fm)
                #pragma unroll
                for (int fn = 0; fn < 4; ++fn)
                    acc[fm][fn] = __builtin_amdgcn_mfma_f32_16x16x32_bf16(
                        af[fm], bf[fn], acc[fm][fn], 0, 0, 0);
        }
        __syncthreads();   // reads done: next stage may overwrite
    }

    // epilogue: score partial = sum_c Aw[c] * tanh(acc + Ub[c] + wah[b][c])
    float ub4[4], aw4[4]; int cidx[4];
    #pragma unroll
    for (int f = 0; f < 4; ++f) {
        const int c = nbk * 128 + wc * 64 + f * 16 + l15;
        cidx[f] = c; ub4[f] = Ub[c]; aw4[f] = Aw[c];
    }
    #pragma unroll
    for (int fm = 0; fm < 4; ++fm) {
        #pragma unroll
        for (int r = 0; r < 4; ++r) {
            const int m = mb * 128 + wr * 64 + fm * 16 + ldr * 4 + r;
            const int b = m / NL;
            const float* wrow = wahb + b * ADIM;
            float s = 0.f;
            #pragma unroll
            for (int f = 0; f < 4; ++f)
                s += aw4[f] * tanhf(acc[fm][f][r] + ub4[f] + wrow[cidx[f]]);
            s += __shfl_xor(s, 1);
            s += __shfl_xor(s, 2);
            s += __shfl_xor(s, 4);
            s += __shfl_xor(s, 8);
            if (l15 == 0) part[(nbk * 2 + wc) * MTOT + m] = s;
        }
    }
}

// ---------------- kernel 4: reduce partials + softmax over L -> alpha ----------------
__global__ void softmax_kernel(const float* __restrict__ part, const float* __restrict__ Ab,
                               float* __restrict__ alpha) {
    const int b = blockIdx.x, t = threadIdx.x;   // 256 threads
    float sv = 0.f;
    if (t < NL) {
        sv = Ab[0];
        #pragma unroll
        for (int p = 0; p < 8; ++p) sv += part[p * MTOT + b * NL + t];
    }
    float v = (t < NL) ? sv : -3.4e38f;
    #pragma unroll
    for (int o = 32; o >= 1; o >>= 1) v = fmaxf(v, __shfl_xor(v, o));
    __shared__ float rm[4], rs[4];
    if ((t & 63) == 0) rm[t >> 6] = v;
    __syncthreads();
    const float bm = fmaxf(fmaxf(rm[0], rm[1]), fmaxf(rm[2], rm[3]));
    const float e = (t < NL) ? expf(sv - bm) : 0.f;
    float s = e;
    #pragma unroll
    for (int o = 32; o >= 1; o >>= 1) s += __shfl_xor(s, o);
    if ((t & 63) == 0) rs[t >> 6] = s;
    __syncthreads();
    const float bs = rs[0] + rs[1] + rs[2] + rs[3];
    if (t < NL) alpha[b * NL + t] = e / bs;
}

// ---------------- kernel 5: context[b][e] = sum_l alpha[b][l] * feat[b][l][e] ----------------
__global__ void context_kernel(const float* __restrict__ feat, const float* __restrict__ alpha,
                               float* __restrict__ ctx) {
    __shared__ float al[NL];
    const int b = blockIdx.x, chunk = blockIdx.y, t = threadIdx.x;  // 128 threads
    for (int i = t; i < NL; i += 128) al[i] = alpha[b * NL + i];
    __syncthreads();
    const int e0 = chunk * 512 + t * 4;
    const float* fp = feat + (size_t)b * NL * ENC + e0;
    f32x4 acc0 = (f32x4){0.f, 0.f, 0.f, 0.f};
    f32x4 acc1 = (f32x4){0.f, 0.f, 0.f, 0.f};
    #pragma unroll 2
    for (int l = 0; l < NL; l += 2) {
        f32x4 f0 = *(const f32x4*)(fp + (size_t)l * ENC);
        f32x4 f1 = *(const f32x4*)(fp + (size_t)(l + 1) * ENC);
        acc0 += al[l] * f0;
        acc1 += al[l + 1] * f1;
    }
    f32x4 rsum = acc0 + acc1;
    *(f32x4*)(ctx + (size_t)b * ENC + e0) = rsum;
}

extern "C" void kernel_launch(void* const* d_in, const int* in_sizes, int n_in,
                              void* d_out, int out_size, void* d_ws, size_t ws_size,
                              hipStream_t stream) {
    const float* feat   = (const float*)d_in[0];
    const float* hidden = (const float*)d_in[1];
    const float* Uw     = (const float*)d_in[2];
    const float* Ub     = (const float*)d_in[3];
    const float* Ww     = (const float*)d_in[4];
    const float* Wb     = (const float*)d_in[5];
    const float* Aw     = (const float*)d_in[6];
    const float* Ab     = (const float*)d_in[7];

    float* out   = (float*)d_out;
    float* alpha = out;              // [128*196]
    float* ctx   = out + MTOT;       // [128*2048]

    char* ws = (char*)d_ws;
    float*          wahb  = (float*)ws;                          // 256 KB
    unsigned short* uwT   = (unsigned short*)(ws + 262144);      // 2 MB
    float*          partb = (float*)(ws + 262144 + 2097152);     // 784 KB

    wah_kernel<<<dim3(128), dim3(512), 0, stream>>>(hidden, Ww, Wb, wahb);
    transpose_uw<<<dim3(64, 16), dim3(32, 8), 0, stream>>>(Uw, uwT);
    gemm_score<<<dim3(784), dim3(256), 0, stream>>>(feat, uwT, Ub, wahb, Aw, partb);
    softmax_kernel<<<dim3(128), dim3(256), 0, stream>>>(partb, Ab, alpha);
    context_kernel<<<dim3(128, 4), dim3(128), 0, stream>>>(feat, alpha, ctx);
}

// Round 13
// 167.653 us; speedup vs baseline: 1.5278x; 1.1198x over previous
//
#include <hip/hip_runtime.h>
#include <hip/hip_bf16.h>

#define ENC 2048
#define ADIM 512
#define DEC 512
#define NBATCH 128
#define NL 196
#define MTOT (NBATCH * NL)   // 25088
#define NKT 32               // K-steps of 64

typedef __attribute__((ext_vector_type(8))) short short8;
typedef __attribute__((ext_vector_type(4))) float f32x4;
typedef __attribute__((ext_vector_type(4))) unsigned int u32x4;

__device__ __forceinline__ unsigned short f2bf(float f) {
    __hip_bfloat16 h = __float2bfloat16(f);
    union { __hip_bfloat16 h; unsigned short u; } cv; cv.h = h; return cv.u;
}
__device__ __forceinline__ unsigned int f2bf2(float lo, float hi) {
    __hip_bfloat162 h = __float22bfloat162_rn(float2{lo, hi});
    union { __hip_bfloat162 h; unsigned int u; } cv; cv.h = h; return cv.u;
}

// async global -> LDS, 16B per lane. lds pointer must be wave-uniform.
__device__ __forceinline__ void load_lds16(const void* g, void* l) {
    __builtin_amdgcn_global_load_lds(
        (const __attribute__((address_space(1))) unsigned int*)g,
        (__attribute__((address_space(3))) unsigned int*)l, 16, 0, 0);
}

// ---------------- kernel 1: w_ah = hidden @ W_w + W_b  [128 x 512] ----------------
__global__ void wah_kernel(const float* __restrict__ hidden, const float* __restrict__ Ww,
                           const float* __restrict__ Wb, float* __restrict__ wah) {
    __shared__ __align__(16) float hs[DEC];
    const int b = blockIdx.x, a = threadIdx.x;   // block 512 threads
    hs[a] = hidden[b * DEC + a];
    __syncthreads();
    float acc = Wb[a];
    #pragma unroll 4
    for (int d = 0; d < DEC; d += 4) {
        f32x4 h = *(const f32x4*)&hs[d];
        acc += h.x * Ww[(d    ) * ADIM + a];
        acc += h.y * Ww[(d + 1) * ADIM + a];
        acc += h.z * Ww[(d + 2) * ADIM + a];
        acc += h.w * Ww[(d + 3) * ADIM + a];
    }
    wah[b * ADIM + a] = acc;
}

// ---------------- kernel 2: U_w [K=2048][N=512] fp32 -> uwT [N][K] bf16 ----------------
__global__ void transpose_uw(const float* __restrict__ Uw, unsigned short* __restrict__ uwT) {
    __shared__ float t[32][33];
    const int k0 = blockIdx.x * 32, n0 = blockIdx.y * 32;
    const int tx = threadIdx.x, ty = threadIdx.y;   // 32 x 8
    #pragma unroll
    for (int i = 0; i < 4; ++i)
        t[ty + 8 * i][tx] = Uw[(size_t)(k0 + ty + 8 * i) * ADIM + n0 + tx];
    __syncthreads();
    #pragma unroll
    for (int i = 0; i < 4; ++i)
        uwT[(size_t)(n0 + ty + 8 * i) * ENC + k0 + tx] = f2bf(t[tx][ty + 8 * i]);
}

// ---------------- kernel 3: BN=512 fused GEMM + tanh + A_w-dot -> COMPLETE scores ----
// One block = 128 rows x ALL 512 cols. Grid 196 (1 block/CU, single round, no tail,
// each A-panel read ONCE — no nbk redundancy, no cvt pre-pass, no score partials).
// 8 waves (512 thr), wave grid 2x4, wave tile 64x128, acc[4][8] (128 VGPR).
// A: fp32 feat via global_load_lds, [128][64] fp32 tile, swizzle slot^=row&15
//    (R12-validated, 0 conflicts), cvt->bf16 at fragment read.
// B: bf16 uwT via global_load_lds, [512][64] tile, swizzle slot^=row&7
//    (R9-validated, 0 conflicts). LDS 98KB, single-buffer 2-barrier m97 loop.
__global__ __launch_bounds__(512, 2) void gemm_score512(
    const float* __restrict__ feat, const unsigned short* __restrict__ uwT,
    const float* __restrict__ Ub, const float* __restrict__ wahb,
    const float* __restrict__ Aw, float* __restrict__ scores)
{
    __shared__ __align__(16) unsigned char As[32768];   // [128][64] fp32 swizzled
    __shared__ __align__(16) unsigned char Bs[65536];   // [512][64] bf16 swizzled
    __shared__ float sred[4][128];

    const int tid  = threadIdx.x;
    const int lane = tid & 63;
    const int w    = tid >> 6;          // 0..7
    const int wr   = w >> 2;            // 0..1 (row half)
    const int wc   = w & 3;             // 0..3 (col quarter)
    const int l15  = lane & 15, ldr = lane >> 4;
    const int mb   = blockIdx.x;        // 0..195

    // ---- A DMA: wave w fills rows [w*16, w*16+16), 4 chunks of 4 rows x 256B ----
    // lane -> row ldr (in chunk), slot l15; source slot pre-swizzled ^ (row&15)
    const float* aS[4];
    #pragma unroll
    for (int c = 0; c < 4; ++c) {
        const int rowc = c * 4 + ldr;                    // 0..15 == row&15
        aS[c] = feat + (size_t)(mb * 128 + w * 16 + rowc) * ENC + ((l15 ^ rowc) << 2);
    }
    // ---- B DMA: wave w fills rows [w*64, w*64+64), 8 chunks of 8 rows x 128B ----
    const unsigned short* bS = uwT
        + (size_t)(w * 64 + (lane >> 3)) * ENC
        + (((lane & 7) ^ ((lane >> 3) & 7)) << 3);

    f32x4 acc[4][8];
    #pragma unroll
    for (int i = 0; i < 4; ++i)
        #pragma unroll
        for (int j = 0; j < 8; ++j)
            acc[i][j] = (f32x4){0.f, 0.f, 0.f, 0.f};

    // read-offset bases (ra&15 == l15, rb&7 == l15&7 since f*16, fn*16 are multiples)
    const int aRowBase = (wr * 64 + l15) * 256;
    const int bRowBase = (wc * 128 + l15) * 128;

    #pragma unroll 1
    for (int kt = 0; kt < NKT; ++kt) {
        #pragma unroll
        for (int c = 0; c < 4; ++c)
            load_lds16(aS[c] + (size_t)kt * 64, As + w * 4096 + c * 1024);
        #pragma unroll
        for (int c = 0; c < 8; ++c)
            load_lds16(bS + (size_t)kt * 64 + c * 8 * ENC, Bs + w * 8192 + c * 1024);
        __syncthreads();   // drains DMA: tile ready

        #pragma unroll
        for (int ks = 0; ks < 2; ++ks) {
            short8 af[4];
            #pragma unroll
            for (int f = 0; f < 4; ++f) {
                const int q0 = (ks * 8 + ldr * 2) ^ l15;
                const int q1 = (ks * 8 + ldr * 2 + 1) ^ l15;
                f32x4 lo = *(const f32x4*)(As + aRowBase + f * 4096 + (q0 << 4));
                f32x4 hi = *(const f32x4*)(As + aRowBase + f * 4096 + (q1 << 4));
                union { unsigned int u[4]; short8 s; } cv;
                cv.u[0] = f2bf2(lo.x, lo.y);
                cv.u[1] = f2bf2(lo.z, lo.w);
                cv.u[2] = f2bf2(hi.x, hi.y);
                cv.u[3] = f2bf2(hi.z, hi.w);
                af[f] = cv.s;
            }
            const int bSlot = (((ks * 4 + ldr) ^ (l15 & 7)) << 4);
            #pragma unroll
            for (int fn = 0; fn < 8; ++fn) {
                short8 bf = *(const short8*)(Bs + bRowBase + fn * 2048 + bSlot);
                #pragma unroll
                for (int fm = 0; fm < 4; ++fm)
                    acc[fm][fn] = __builtin_amdgcn_mfma_f32_16x16x32_bf16(
                        af[fm], bf, acc[fm][fn], 0, 0, 0);
            }
        }
        __syncthreads();   // reads done: next stage may overwrite
    }

    // ---- epilogue: complete score rows (sum over this wave's 128 cols, then x4 waves) ----
    float ub8[8], aw8[8]; int cidx[8];
    #pragma unroll
    for (int fn = 0; fn < 8; ++fn) {
        const int c = wc * 128 + fn * 16 + l15;
        cidx[fn] = c; ub8[fn] = Ub[c]; aw8[fn] = Aw[c];
    }
    #pragma unroll
    for (int fm = 0; fm < 4; ++fm) {
        #pragma unroll
        for (int r = 0; r < 4; ++r) {
            const int lr = wr * 64 + fm * 16 + ldr * 4 + r;     // 0..127
            const int m  = mb * 128 + lr;
            const int b  = m / NL;
            const float* wrow = wahb + b * ADIM;
            float s = 0.f;
            #pragma unroll
            for (int fn = 0; fn < 8; ++fn)
                s += aw8[fn] * tanhf(acc[fm][fn][r] + ub8[fn] + wrow[cidx[fn]]);
            s += __shfl_xor(s, 1);
            s += __shfl_xor(s, 2);
            s += __shfl_xor(s, 4);
            s += __shfl_xor(s, 8);
            if (l15 == 0) sred[wc][lr] = s;
        }
    }
    __syncthreads();
    if (tid < 128)
        scores[mb * 128 + tid] = sred[0][tid] + sred[1][tid] + sred[2][tid] + sred[3][tid];
}

// ---------------- kernel 4: softmax over L -> alpha ----------------
__global__ void softmax_kernel(const float* __restrict__ scores, const float* __restrict__ Ab,
                               float* __restrict__ alpha) {
    const int b = blockIdx.x, t = threadIdx.x;   // 256 threads
    float sv = 0.f;
    if (t < NL) sv = scores[b * NL + t] + Ab[0];
    float v = (t < NL) ? sv : -3.4e38f;
    #pragma unroll
    for (int o = 32; o >= 1; o >>= 1) v = fmaxf(v, __shfl_xor(v, o));
    __shared__ float rm[4], rs[4];
    if ((t & 63) == 0) rm[t >> 6] = v;
    __syncthreads();
    const float bm = fmaxf(fmaxf(rm[0], rm[1]), fmaxf(rm[2], rm[3]));
    const float e = (t < NL) ? expf(sv - bm) : 0.f;
    float s = e;
    #pragma unroll
    for (int o = 32; o >= 1; o >>= 1) s += __shfl_xor(s, o);
    if ((t & 63) == 0) rs[t >> 6] = s;
    __syncthreads();
    const float bs = rs[0] + rs[1] + rs[2] + rs[3];
    if (t < NL) alpha[b * NL + t] = e / bs;
}

// ---------------- kernel 5: context[b][e] = sum_l alpha[b][l] * feat[b][l][e] ----------------
__global__ void context_kernel(const float* __restrict__ feat, const float* __restrict__ alpha,
                               float* __restrict__ ctx) {
    __shared__ float al[NL];
    const int b = blockIdx.x, chunk = blockIdx.y, t = threadIdx.x;  // 128 threads
    for (int i = t; i < NL; i += 128) al[i] = alpha[b * NL + i];
    __syncthreads();
    const int e0 = chunk * 512 + t * 4;
    const float* fp = feat + (size_t)b * NL * ENC + e0;
    f32x4 acc0 = (f32x4){0.f, 0.f, 0.f, 0.f};
    f32x4 acc1 = (f32x4){0.f, 0.f, 0.f, 0.f};
    #pragma unroll 2
    for (int l = 0; l < NL; l += 2) {
        f32x4 f0 = *(const f32x4*)(fp + (size_t)l * ENC);
        f32x4 f1 = *(const f32x4*)(fp + (size_t)(l + 1) * ENC);
        acc0 += al[l] * f0;
        acc1 += al[l + 1] * f1;
    }
    f32x4 rsum = acc0 + acc1;
    *(f32x4*)(ctx + (size_t)b * ENC + e0) = rsum;
}

extern "C" void kernel_launch(void* const* d_in, const int* in_sizes, int n_in,
                              void* d_out, int out_size, void* d_ws, size_t ws_size,
                              hipStream_t stream) {
    const float* feat   = (const float*)d_in[0];
    const float* hidden = (const float*)d_in[1];
    const float* Uw     = (const float*)d_in[2];
    const float* Ub     = (const float*)d_in[3];
    const float* Ww     = (const float*)d_in[4];
    const float* Wb     = (const float*)d_in[5];
    const float* Aw     = (const float*)d_in[6];
    const float* Ab     = (const float*)d_in[7];

    float* out   = (float*)d_out;
    float* alpha = out;              // [128*196]
    float* ctx   = out + MTOT;       // [128*2048]

    char* ws = (char*)d_ws;
    float*          wahb   = (float*)ws;                          // 256 KB
    unsigned short* uwT    = (unsigned short*)(ws + 262144);      // 2 MB
    float*          scores = (float*)(ws + 262144 + 2097152);     // 100 KB

    wah_kernel<<<dim3(128), dim3(512), 0, stream>>>(hidden, Ww, Wb, wahb);
    transpose_uw<<<dim3(64, 16), dim3(32, 8), 0, stream>>>(Uw, uwT);
    gemm_score512<<<dim3(196), dim3(512), 0, stream>>>(feat, uwT, Ub, wahb, Aw, scores);
    softmax_kernel<<<dim3(128), dim3(256), 0, stream>>>(scores, Ab, alpha);
    context_kernel<<<dim3(128, 4), dim3(128), 0, stream>>>(feat, alpha, ctx);
}